// Round 9
// baseline (483.794 us; speedup 1.0000x reference)
//
#include <hip/hip_runtime.h>
#include <hip/hip_bf16.h>

#define DD 64      // feature dim K
#define TN 128     // output rows per block  (X1 rows)
#define TM 256     // output cols per block  (X2 rows)

// DIAGNOSTIC ROUND: identical work repeated 3x so our dispatch (~230us)
// outlasts the harness fill kernels (~155us) and surfaces in the rocprof
// top-5 with full counters (FETCH_SIZE / WRITE_SIZE / MfmaUtil / VALUBusy /
// SQ_LDS_BANK_CONFLICT). Output is rewritten with identical values each rep
// (deterministic, passes re-validation).
#define REPS 3

typedef short short8 __attribute__((ext_vector_type(8)));
typedef unsigned short us8 __attribute__((ext_vector_type(8)));
typedef float f32x4 __attribute__((ext_vector_type(4)));

__device__ __forceinline__ float bf2f(unsigned short h) {
    union { unsigned u; float f; } v; v.u = ((unsigned)h) << 16;
    return v.f;
}
__device__ __forceinline__ unsigned short f2bf(float x) {
    __hip_bfloat16 b = __float2bfloat16(x);
    unsigned short u;
    __builtin_memcpy(&u, &b, 2);
    return u;
}

__global__ __launch_bounds__(256, 2) void sqexp_kernel(
    const float* __restrict__ X1, const float* __restrict__ X2,
    const float* __restrict__ lp, const float* __restrict__ sfp,
    float* __restrict__ out, int N, int M)
{
    __shared__ __align__(16) unsigned char ldsbuf[TM * DD * 2 * 2];
    __shared__ float sq1[TN];
    __shared__ float sq2[TM];

    unsigned short* Bh = (unsigned short*)ldsbuf;
    unsigned short* Bl = (unsigned short*)(ldsbuf + TM * DD * 2);

    const int t    = threadIdx.x;
    const int w    = t >> 6;
    const int lane = t & 63;
    const int n0   = blockIdx.y * TN;
    const int m0   = blockIdx.x * TM;

    const int wr = (w >> 1) * 64;    // 2x2 wave grid: each wave 64 rows x 128 cols
    const int wc = (w & 1) * 128;

    for (int rep = 0; rep < REPS; ++rep) {

    // ---- B staging: one X2 row per thread -> hi/lo bf16 LDS (swizzled) + sq2 ----
    {
        const float4* Bp = (const float4*)(X2 + (size_t)(m0 + t) * DD);
        float4 bv[16];
        #pragma unroll
        for (int j = 0; j < 16; ++j) bv[j] = Bp[j];

        float s2 = 0.0f;
        #pragma unroll
        for (int c = 0; c < 8; ++c) {
            float4 f0 = bv[2 * c], f1 = bv[2 * c + 1];
            float xs[8] = { f0.x, f0.y, f0.z, f0.w, f1.x, f1.y, f1.z, f1.w };
            us8 hv, lv;
            #pragma unroll
            for (int e = 0; e < 8; ++e) {
                s2 = fmaf(xs[e], xs[e], s2);
                unsigned short h = f2bf(xs[e]);
                hv[e] = h;
                lv[e] = f2bf(xs[e] - bf2f(h));
            }
            int byte = t * 128 + ((c * 16) ^ ((t & 7) << 4));
            *(us8*)&Bh[byte >> 1] = hv;
            *(us8*)&Bl[byte >> 1] = lv;
        }
        sq2[t] = s2;
    }

    // ---- A fragments straight into registers + sq1 ----
    short8 ah[4][2], al[4][2];       // [fm][ks]
    #pragma unroll
    for (int fm = 0; fm < 4; ++fm) {
        const int row = n0 + wr + fm * 16 + (lane & 15);
        const float4* Ap = (const float4*)(X1 + (size_t)row * DD) + (lane >> 4) * 2;
        float p = 0.0f;
        #pragma unroll
        for (int ks = 0; ks < 2; ++ks) {
            float4 f0 = Ap[ks * 8];
            float4 f1 = Ap[ks * 8 + 1];
            float xs[8] = { f0.x, f0.y, f0.z, f0.w, f1.x, f1.y, f1.z, f1.w };
            us8 hv, lv;
            #pragma unroll
            for (int e = 0; e < 8; ++e) {
                p = fmaf(xs[e], xs[e], p);
                unsigned short h = f2bf(xs[e]);
                hv[e] = h;
                lv[e] = f2bf(xs[e] - bf2f(h));
            }
            __builtin_memcpy(&ah[fm][ks], &hv, 16);
            __builtin_memcpy(&al[fm][ks], &lv, 16);
        }
        p += __shfl_xor(p, 16);
        p += __shfl_xor(p, 32);
        if ((w & 1) == 0 && (lane >> 4) == 0) sq1[wr + fm * 16 + lane] = p;
    }
    __syncthreads();                 // b1: B tile + sq in LDS

    // ---- MFMA: cross = hiA*hiB + hiA*loB + loA*hiB ----
    f32x4 acc[4][8] = {};
    #pragma unroll
    for (int ks = 0; ks < 2; ++ks) {
        #pragma unroll
        for (int fn = 0; fn < 8; ++fn) {
            int brow = wc + fn * 16 + (lane & 15);
            int byte = brow * 128 + (((ks * 64) + (lane >> 4) * 16) ^ ((brow & 7) << 4));
            short8 bh = *(const short8*)&Bh[byte >> 1];
            short8 bl = *(const short8*)&Bl[byte >> 1];
            #pragma unroll
            for (int fm = 0; fm < 4; ++fm) {
                acc[fm][fn] = __builtin_amdgcn_mfma_f32_16x16x32_bf16(bh, ah[fm][ks], acc[fm][fn], 0, 0, 0);
                acc[fm][fn] = __builtin_amdgcn_mfma_f32_16x16x32_bf16(bl, ah[fm][ks], acc[fm][fn], 0, 0, 0);
                acc[fm][fn] = __builtin_amdgcn_mfma_f32_16x16x32_bf16(bh, al[fm][ks], acc[fm][fn], 0, 0, 0);
            }
        }
    }
    __syncthreads();                 // b2: all B-LDS reads done -> alias as Obuf

    const float lv_ = lp[0], sf = sfp[0];
    const float c1  = -0.5f / (lv_ * lv_);
    const float cm2 = -2.0f * c1;
    const float amp = sf * sf;

    float a1[4];
    #pragma unroll
    for (int fm = 0; fm < 4; ++fm) a1[fm] = c1 * sq1[wr + fm * 16 + (lane & 15)];

    // ---- two store phases: phase p covers block rows [64p, 64p+64) ----
    #pragma unroll
    for (int p = 0; p < 2; ++p) {
        if ((w >> 1) == p) {
            #pragma unroll
            for (int fn = 0; fn < 8; ++fn) {
                f32x4 s  = *(const f32x4*)&sq2[wc + fn * 16 + (lane >> 4) * 4];
                f32x4 a2 = c1 * s;
                #pragma unroll
                for (int fm = 0; fm < 4; ++fm) {
                    f32x4 o;
                    #pragma unroll
                    for (int r = 0; r < 4; ++r) {
                        float arg = fminf(fmaf(cm2, acc[fm][fn][r], a1[fm] + a2[r]), 0.0f);
                        o[r] = amp * __expf(arg);
                    }
                    int R = fm * 16 + (lane & 15);               // phase-local row
                    int C = wc + fn * 16 + (lane >> 4) * 4;
                    *(f32x4*)(ldsbuf + R * 1024 + ((C * 4) ^ ((R & 7) << 4))) = o;
                }
            }
        }
        __syncthreads();             // Obuf(phase p) complete

        #pragma unroll
        for (int i = 0; i < 16; ++i) {
            int R = w * 16 + i;
            f32x4 v = *(const f32x4*)(ldsbuf + R * 1024 + ((lane ^ (R & 7)) * 16));
            size_t off = (size_t)(n0 + p * 64 + R) * M + m0 + 4 * lane;
            *(f32x4*)&out[off] = v;
        }
        __syncthreads();             // Obuf reads done before reuse
    }

    }  // rep
}

extern "C" void kernel_launch(void* const* d_in, const int* in_sizes, int n_in,
                              void* d_out, int out_size, void* d_ws, size_t ws_size,
                              hipStream_t stream) {
    const float* X1 = (const float*)d_in[0];
    const float* X2 = (const float*)d_in[1];
    const float* lp = (const float*)d_in[2];
    const float* sf = (const float*)d_in[3];
    float* out = (float*)d_out;
    const int N = in_sizes[0] / DD;
    const int M = in_sizes[1] / DD;
    dim3 grid(M / TM, N / TN);   // 32 x 64 = 2048 blocks
    sqexp_kernel<<<grid, 256, 0, stream>>>(X1, X2, lp, sf, out, N, M);
}

// Round 10
// 152.546 us; speedup vs baseline: 3.1715x; 3.1715x over previous
//
#include <hip/hip_runtime.h>
#include <hip/hip_bf16.h>

#define DD 64        // feature dim K
#define TM 128       // cols per block (X2 rows) — fixed panel, B staged once
#define TROWS 128    // X1 rows per tile
#define NTILES 8     // tiles per block -> block covers 1024 rows x 128 cols

typedef short short8 __attribute__((ext_vector_type(8)));
typedef unsigned short us8 __attribute__((ext_vector_type(8)));
typedef float f32x4 __attribute__((ext_vector_type(4)));

__device__ __forceinline__ float bf2f(unsigned short h) {
    union { unsigned u; float f; } v; v.u = ((unsigned)h) << 16;
    return v.f;
}
__device__ __forceinline__ unsigned short f2bf(float x) {
    __hip_bfloat16 b = __float2bfloat16(x);
    unsigned short u;
    __builtin_memcpy(&u, &b, 2);
    return u;
}

__global__ __launch_bounds__(256, 2) void sqexp_kernel(
    const float* __restrict__ X1, const float* __restrict__ X2,
    const float* __restrict__ lp, const float* __restrict__ sfp,
    float* __restrict__ out, int N, int M)
{
    __shared__ __align__(16) unsigned char Bbuf[TM * DD * 2 * 2];  // 32KB hi|lo bf16
    __shared__ __align__(16) unsigned char Obuf[4 * 8192];         // 32KB, 8KB per wave (PRIVATE)
    __shared__ float sq2[TM];

    unsigned short* Bh = (unsigned short*)Bbuf;
    unsigned short* Bl = (unsigned short*)(Bbuf + TM * DD * 2);

    const int t    = threadIdx.x;
    const int w    = t >> 6;
    const int lane = t & 63;

    const int npx     = M / TM;                 // 64 col panels
    const int bx      = blockIdx.x % npx;
    const int by      = blockIdx.x / npx;
    const int m0      = bx * TM;
    const int rowband = by * (TROWS * NTILES);

    const float lv_ = lp[0], sf = sfp[0];
    const float c1  = -0.5f / (lv_ * lv_);
    const float cm2 = -2.0f * c1;
    const float amp = sf * sf;

    // ---- stage B once: 2 threads per X2 row -> hi/lo LDS (swizzled) + sq2 ----
    {
        const int brow = t >> 1, half = t & 1;
        const float4* Bp = (const float4*)(X2 + (size_t)(m0 + brow) * DD) + half * 8;
        float4 f[8];
        #pragma unroll
        for (int j = 0; j < 8; ++j) f[j] = Bp[j];

        float s2 = 0.0f;
        #pragma unroll
        for (int c = 0; c < 4; ++c) {
            float4 f0 = f[2 * c], f1 = f[2 * c + 1];
            float xs[8] = { f0.x, f0.y, f0.z, f0.w, f1.x, f1.y, f1.z, f1.w };
            us8 hv, lv;
            #pragma unroll
            for (int e = 0; e < 8; ++e) {
                s2 = fmaf(xs[e], xs[e], s2);
                unsigned short h = f2bf(xs[e]);
                hv[e] = h;
                lv[e] = f2bf(xs[e] - bf2f(h));
            }
            int byte = brow * 128 + (((half * 4 + c) * 16) ^ ((brow & 7) << 4));
            *(us8*)&Bh[byte >> 1] = hv;
            *(us8*)&Bl[byte >> 1] = lv;
        }
        s2 += __shfl_xor(s2, 1);
        if (half == 0) sq2[brow] = s2;
    }

    // ---- A prefetch/convert helpers (per-lane direct gather, no LDS) ----
    float4 pre[2][2][2];             // [fm][ks][j]
    auto issueA = [&](int tt) {
        #pragma unroll
        for (int fm = 0; fm < 2; ++fm) {
            const int row = rowband + tt * TROWS + w * 32 + fm * 16 + (lane & 15);
            const float4* Ap = (const float4*)(X1 + (size_t)row * DD) + (lane >> 4) * 2;
            pre[fm][0][0] = Ap[0];
            pre[fm][0][1] = Ap[1];
            pre[fm][1][0] = Ap[8];
            pre[fm][1][1] = Ap[9];
        }
    };
    short8 ah[2][2], al[2][2];
    float a1[2];
    auto convertA = [&]() {
        #pragma unroll
        for (int fm = 0; fm < 2; ++fm) {
            float p = 0.0f;
            #pragma unroll
            for (int ks = 0; ks < 2; ++ks) {
                float4 f0 = pre[fm][ks][0], f1 = pre[fm][ks][1];
                float xs[8] = { f0.x, f0.y, f0.z, f0.w, f1.x, f1.y, f1.z, f1.w };
                us8 hv, lv;
                #pragma unroll
                for (int e = 0; e < 8; ++e) {
                    p = fmaf(xs[e], xs[e], p);
                    unsigned short h = f2bf(xs[e]);
                    hv[e] = h;
                    lv[e] = f2bf(xs[e] - bf2f(h));
                }
                __builtin_memcpy(&ah[fm][ks], &hv, 16);
                __builtin_memcpy(&al[fm][ks], &lv, 16);
            }
            p += __shfl_xor(p, 16);
            p += __shfl_xor(p, 32);
            a1[fm] = c1 * p;
        }
    };

    issueA(0);
    convertA();
    __syncthreads();                 // the ONLY block-wide barrier

    unsigned char* myO = Obuf + w * 8192;   // wave-private out staging (16 rows x 512B)

    for (int tt = 0; tt < NTILES; ++tt) {
        // prefetch next tile's A (latency hides under MFMA + epilogue + stores)
        if (tt + 1 < NTILES) issueA(tt + 1);

        // ---- MFMA: cross = hiA*hiB + hiA*loB + loA*hiB (B as intrinsic-A so
        //      C/D reg index walks the M/contiguous dim) ----
        f32x4 acc[2][8] = {};
        #pragma unroll
        for (int ks = 0; ks < 2; ++ks) {
            #pragma unroll
            for (int fn = 0; fn < 8; ++fn) {
                int brow = fn * 16 + (lane & 15);
                int byte = brow * 128 + (((ks * 64) + (lane >> 4) * 16) ^ ((brow & 7) << 4));
                short8 bh = *(const short8*)&Bh[byte >> 1];
                short8 bl = *(const short8*)&Bl[byte >> 1];
                #pragma unroll
                for (int fm = 0; fm < 2; ++fm) {
                    acc[fm][fn] = __builtin_amdgcn_mfma_f32_16x16x32_bf16(bh, ah[fm][ks], acc[fm][fn], 0, 0, 0);
                    acc[fm][fn] = __builtin_amdgcn_mfma_f32_16x16x32_bf16(bl, ah[fm][ks], acc[fm][fn], 0, 0, 0);
                    acc[fm][fn] = __builtin_amdgcn_mfma_f32_16x16x32_bf16(bh, al[fm][ks], acc[fm][fn], 0, 0, 0);
                }
            }
        }

        // ---- epilogue + store, wave-private, 2 phases of 16 rows; no barriers.
        //      (DS ops execute in issue order within a wave -> WAR safe.) ----
        #pragma unroll
        for (int fm = 0; fm < 2; ++fm) {
            #pragma unroll
            for (int fn = 0; fn < 8; ++fn) {
                f32x4 s  = *(const f32x4*)&sq2[fn * 16 + (lane >> 4) * 4];
                f32x4 a2 = c1 * s;
                f32x4 o;
                #pragma unroll
                for (int r = 0; r < 4; ++r) {
                    float arg = fminf(fmaf(cm2, acc[fm][fn][r], a1[fm] + a2[r]), 0.0f);
                    o[r] = amp * __expf(arg);
                }
                int R = lane & 15;
                int C = fn * 16 + (lane >> 4) * 4;
                *(f32x4*)(myO + R * 512 + ((C * 4) ^ ((R & 7) << 4))) = o;
            }
            #pragma unroll
            for (int i = 0; i < 8; ++i) {
                int R = i * 2 + (lane >> 5);         // 2 rows per instr, 512B each
                int c = lane & 31;
                f32x4 v = *(const f32x4*)(myO + R * 512 + ((c ^ (R & 7)) * 16));
                size_t row = (size_t)(rowband + tt * TROWS + w * 32 + fm * 16 + R);
                *(f32x4*)&out[row * M + m0 + 4 * c] = v;
            }
        }

        // convert next tile's A (loads issued at top of this iter)
        if (tt + 1 < NTILES) convertA();
    }
}

extern "C" void kernel_launch(void* const* d_in, const int* in_sizes, int n_in,
                              void* d_out, int out_size, void* d_ws, size_t ws_size,
                              hipStream_t stream) {
    const float* X1 = (const float*)d_in[0];
    const float* X2 = (const float*)d_in[1];
    const float* lp = (const float*)d_in[2];
    const float* sf = (const float*)d_in[3];
    float* out = (float*)d_out;
    const int N = in_sizes[0] / DD;
    const int M = in_sizes[1] / DD;
    const int nblk = (M / TM) * (N / (TROWS * NTILES));   // 64 x 8 = 512 (= 2/CU)
    sqexp_kernel<<<nblk, 256, 0, stream>>>(X1, X2, lp, sf, out, N, M);
}

// Round 11
// 95.818 us; speedup vs baseline: 5.0491x; 1.5920x over previous
//
#include <hip/hip_runtime.h>
#include <hip/hip_bf16.h>

#define DD 64      // feature dim K
#define TN 256     // output rows per block (X1 rows)
#define TM 128     // output cols per block (X2 rows)

typedef short short8 __attribute__((ext_vector_type(8)));
typedef unsigned short us8 __attribute__((ext_vector_type(8)));
typedef float f32x4 __attribute__((ext_vector_type(4)));

__device__ __forceinline__ float bf2f(unsigned short h) {
    union { unsigned u; float f; } v; v.u = ((unsigned)h) << 16;
    return v.f;
}
__device__ __forceinline__ unsigned short f2bf(float x) {
    __hip_bfloat16 b = __float2bfloat16(x);
    unsigned short u;
    __builtin_memcpy(&u, &b, 2);
    return u;
}

__global__ __launch_bounds__(512, 2) void sqexp_kernel(
    const float* __restrict__ X1, const float* __restrict__ X2,
    const float* __restrict__ lp, const float* __restrict__ sfp,
    float* __restrict__ out, int N, int M)
{
    // Disjoint LDS: B hi/lo tiles (32KB) + out-staging (32KB) — no aliasing.
    __shared__ __align__(16) unsigned char Bbuf[TM * DD * 2 * 2];
    __shared__ __align__(16) unsigned char Obuf[64 * 512];
    __shared__ float sq2[TM];

    unsigned short* Bh = (unsigned short*)Bbuf;
    unsigned short* Bl = (unsigned short*)(Bbuf + TM * DD * 2);

    const int t    = threadIdx.x;
    const int w    = t >> 6;         // 8 waves: 4 row x 2 col grid of 64x64 tiles
    const int lane = t & 63;
    const int wr   = (w >> 1) * 64;
    const int wc   = (w & 1) * 64;

    // ---- L2-blocked, XCD-aware block mapping ----
    // XCD k = F%8 owns column slab bx in [8k, 8k+8). Within the slab, launch
    // order l = F/8 walks 8by x 4bx patches (32 blocks) so the ~32 co-resident
    // blocks per XCD share a ~640KB input working set (fits 4MB L2).
    const int F      = blockIdx.x;
    const int k      = F & 7;
    const int l      = F >> 3;           // [0,256)
    const int patch  = l >> 5;           // [0,8): pbx = patch&1, pby = patch>>1
    const int within = l & 31;           // 4bx x 8by
    const int bx     = k * 8 + (patch & 1) * 4 + (within & 3);
    const int by     = (patch >> 1) * 8 + (within >> 2);
    const int n0     = by * TN;
    const int m0     = bx * TM;

    const float lv_ = lp[0], sf = sfp[0];
    const float c1  = -0.5f / (lv_ * lv_);
    const float cm2 = -2.0f * c1;
    const float amp = sf * sf;

    // ---- B staging: 4 threads per X2 row (64B each) -> hi/lo LDS + sq2 ----
    {
        const int row = t >> 2, q = t & 3;
        const float4* Bp = (const float4*)(X2 + (size_t)(m0 + row) * DD) + q * 4;
        float4 f[4];
        #pragma unroll
        for (int j = 0; j < 4; ++j) f[j] = Bp[j];

        float s2 = 0.0f;
        #pragma unroll
        for (int c = 0; c < 2; ++c) {
            float4 f0 = f[2 * c], f1 = f[2 * c + 1];
            float xs[8] = { f0.x, f0.y, f0.z, f0.w, f1.x, f1.y, f1.z, f1.w };
            us8 hv, lv;
            #pragma unroll
            for (int e = 0; e < 8; ++e) {
                s2 = fmaf(xs[e], xs[e], s2);
                unsigned short h = f2bf(xs[e]);
                hv[e] = h;
                lv[e] = f2bf(xs[e] - bf2f(h));
            }
            int byte = row * 128 + (((q * 2 + c) * 16) ^ ((row & 7) << 4));
            *(us8*)&Bh[byte >> 1] = hv;
            *(us8*)&Bl[byte >> 1] = lv;
        }
        s2 += __shfl_xor(s2, 1);
        s2 += __shfl_xor(s2, 2);
        if (q == 0) sq2[row] = s2;
    }

    // ---- A fragments into registers (per-lane gather) + in-register sq1 ----
    short8 ah[4][2], al[4][2];       // [fm][ks]
    float a1[4];
    #pragma unroll
    for (int fm = 0; fm < 4; ++fm) {
        const int row = n0 + wr + fm * 16 + (lane & 15);
        const float4* Ap = (const float4*)(X1 + (size_t)row * DD) + (lane >> 4) * 2;
        float p = 0.0f;
        #pragma unroll
        for (int ks = 0; ks < 2; ++ks) {
            float4 f0 = Ap[ks * 8];
            float4 f1 = Ap[ks * 8 + 1];
            float xs[8] = { f0.x, f0.y, f0.z, f0.w, f1.x, f1.y, f1.z, f1.w };
            us8 hv, lv;
            #pragma unroll
            for (int e = 0; e < 8; ++e) {
                p = fmaf(xs[e], xs[e], p);
                unsigned short h = f2bf(xs[e]);
                hv[e] = h;
                lv[e] = f2bf(xs[e] - bf2f(h));
            }
            __builtin_memcpy(&ah[fm][ks], &hv, 16);
            __builtin_memcpy(&al[fm][ks], &lv, 16);
        }
        p += __shfl_xor(p, 16);
        p += __shfl_xor(p, 32);
        a1[fm] = c1 * p;
    }
    __syncthreads();                 // B tile + sq2 ready

    // ---- MFMA: cross = hiA*hiB + hiA*loB + loA*hiB (B as intrinsic-A so the
    //      C/D reg index walks the M/contiguous dim) ----
    f32x4 acc[4][4] = {};
    #pragma unroll
    for (int ks = 0; ks < 2; ++ks) {
        #pragma unroll
        for (int fn = 0; fn < 4; ++fn) {
            int brow = wc + fn * 16 + (lane & 15);
            int byte = brow * 128 + (((ks * 64) + (lane >> 4) * 16) ^ ((brow & 7) << 4));
            short8 bh = *(const short8*)&Bh[byte >> 1];
            short8 bl = *(const short8*)&Bl[byte >> 1];
            #pragma unroll
            for (int fm = 0; fm < 4; ++fm) {
                acc[fm][fn] = __builtin_amdgcn_mfma_f32_16x16x32_bf16(bh, ah[fm][ks], acc[fm][fn], 0, 0, 0);
                acc[fm][fn] = __builtin_amdgcn_mfma_f32_16x16x32_bf16(bl, ah[fm][ks], acc[fm][fn], 0, 0, 0);
                acc[fm][fn] = __builtin_amdgcn_mfma_f32_16x16x32_bf16(bh, al[fm][ks], acc[fm][fn], 0, 0, 0);
            }
        }
    }

    // ---- 4 store phases: phase p covers block rows [64p, 64p+64) ----
    #pragma unroll
    for (int p = 0; p < 4; ++p) {
        if ((w >> 1) == p) {         // the two waves owning these 64 rows
            #pragma unroll
            for (int fn = 0; fn < 4; ++fn) {
                f32x4 s  = *(const f32x4*)&sq2[wc + fn * 16 + (lane >> 4) * 4];
                f32x4 a2 = c1 * s;
                #pragma unroll
                for (int fm = 0; fm < 4; ++fm) {
                    f32x4 o;
                    #pragma unroll
                    for (int r = 0; r < 4; ++r) {
                        float arg = fminf(fmaf(cm2, acc[fm][fn][r], a1[fm] + a2[r]), 0.0f);
                        o[r] = amp * __expf(arg);
                    }
                    int R = fm * 16 + (lane & 15);            // phase-local row
                    int C = wc + fn * 16 + (lane >> 4) * 4;   // tile col [0,128)
                    *(f32x4*)(Obuf + R * 512 + ((C * 4) ^ ((R & 7) << 4))) = o;
                }
            }
        }
        __syncthreads();             // Obuf(phase p) complete

        // streaming store: all 8 waves, 2 rows x 512B contiguous per instr
        #pragma unroll
        for (int i = 0; i < 4; ++i) {
            int R = w * 8 + i * 2 + (lane >> 5);
            int c = lane & 31;
            f32x4 v = *(const f32x4*)(Obuf + R * 512 + ((c ^ (R & 7)) * 16));
            size_t off = (size_t)(n0 + p * 64 + R) * M + m0 + 4 * c;
            __builtin_nontemporal_store(v, (f32x4*)&out[off]);
        }
        __syncthreads();             // Obuf reads done before next phase
    }
}

extern "C" void kernel_launch(void* const* d_in, const int* in_sizes, int n_in,
                              void* d_out, int out_size, void* d_ws, size_t ws_size,
                              hipStream_t stream) {
    const float* X1 = (const float*)d_in[0];
    const float* X2 = (const float*)d_in[1];
    const float* lp = (const float*)d_in[2];
    const float* sf = (const float*)d_in[3];
    float* out = (float*)d_out;
    const int N = in_sizes[0] / DD;
    const int M = in_sizes[1] / DD;
    const int nblk = (N / TN) * (M / TM);   // 32 x 64 = 2048
    sqexp_kernel<<<nblk, 512, 0, stream>>>(X1, X2, lp, sf, out, N, M);
}

// Round 12
// 81.935 us; speedup vs baseline: 5.9046x; 1.1694x over previous
//
#include <hip/hip_runtime.h>
#include <hip/hip_bf16.h>

#define DD 64      // feature dim K
#define TN 64      // rows per block (X1)
#define TM 128     // cols per sub-tile (X2); each block does 2 column-adjacent sub-tiles

typedef short short8 __attribute__((ext_vector_type(8)));
typedef unsigned short us8 __attribute__((ext_vector_type(8)));
typedef float f32x4 __attribute__((ext_vector_type(4)));

__device__ __forceinline__ float bf2f(unsigned short h) {
    union { unsigned u; float f; } v; v.u = ((unsigned)h) << 16;
    return v.f;
}
__device__ __forceinline__ unsigned short f2bf(float x) {
    __hip_bfloat16 b = __float2bfloat16(x);
    unsigned short u;
    __builtin_memcpy(&u, &b, 2);
    return u;
}

// lgkm-only workgroup barrier: orders LDS (ds) ops across the block WITHOUT
// draining outstanding global stores (vmcnt). __syncthreads() would emit
// s_waitcnt vmcnt(0) and serialize the store stream against compute.
__device__ __forceinline__ void barrier_lgkm() {
    __builtin_amdgcn_sched_barrier(0);
    asm volatile("s_waitcnt lgkmcnt(0)" ::: "memory");
    __builtin_amdgcn_s_barrier();
    __builtin_amdgcn_sched_barrier(0);
}

__global__ __launch_bounds__(256, 2) void sqexp_kernel(
    const float* __restrict__ X1, const float* __restrict__ X2,
    const float* __restrict__ lp, const float* __restrict__ sfp,
    float* __restrict__ out, int N, int M)
{
    // Disjoint regions — no aliasing: B tiles (hi|lo, 32KB) + out-stage (32KB).
    __shared__ __align__(16) unsigned char Bbuf[2 * TM * DD * 2];
    __shared__ __align__(16) unsigned char Obuf[TN * TM * 4];
    __shared__ float sq1[TN];
    __shared__ float sq2[TM];

    unsigned short* Bh = (unsigned short*)Bbuf;
    unsigned short* Bl = (unsigned short*)(Bbuf + TM * DD * 2);

    const int t    = threadIdx.x;
    const int w    = t >> 6;
    const int lane = t & 63;
    const int n0   = blockIdx.y * TN;
    const int m0   = blockIdx.x * (2 * TM);

    const int wr = (w >> 1) * 32;    // 2x2 wave grid: 32 rows x 64 cols each
    const int wc = (w & 1) * 64;

    const float lv_ = lp[0], sf = sfp[0];
    const float c1  = -0.5f / (lv_ * lv_);
    const float cm2 = -2.0f * c1;
    const float amp = sf * sf;

    const int brow_ = t >> 1;        // B staging: 2 threads per X2 row
    const int bhalf = t & 1;

    // ---- helpers ----
    auto loadB = [&](int mbase, float4 (&f)[8]) {
        const float4* Bp = (const float4*)(X2 + (size_t)(mbase + brow_) * DD) + bhalf * 8;
        #pragma unroll
        for (int j = 0; j < 8; ++j) f[j] = Bp[j];
    };
    auto writeB = [&](float4 (&f)[8]) {
        float s2 = 0.0f;
        #pragma unroll
        for (int c = 0; c < 4; ++c) {
            float4 f0 = f[2 * c], f1 = f[2 * c + 1];
            float xs[8] = { f0.x, f0.y, f0.z, f0.w, f1.x, f1.y, f1.z, f1.w };
            us8 hv, lv;
            #pragma unroll
            for (int e = 0; e < 8; ++e) {
                s2 = fmaf(xs[e], xs[e], s2);
                unsigned short h = f2bf(xs[e]);
                hv[e] = h;
                lv[e] = f2bf(xs[e] - bf2f(h));
            }
            int byte = brow_ * 128 + (((bhalf * 4 + c) * 16) ^ ((brow_ & 7) << 4));
            *(us8*)&Bh[byte >> 1] = hv;
            *(us8*)&Bl[byte >> 1] = lv;
        }
        s2 += __shfl_xor(s2, 1);
        if (bhalf == 0) sq2[brow_] = s2;
    };

    short8 ah[2][2], al[2][2];       // [fm][ks]
    auto computeTile = [&](f32x4 (&acc)[2][4]) {
        #pragma unroll
        for (int ks = 0; ks < 2; ++ks) {
            #pragma unroll
            for (int fn = 0; fn < 4; ++fn) {
                int br   = wc + fn * 16 + (lane & 15);
                int byte = br * 128 + (((ks * 64) + (lane >> 4) * 16) ^ ((br & 7) << 4));
                short8 bh = *(const short8*)&Bh[byte >> 1];
                short8 bl = *(const short8*)&Bl[byte >> 1];
                #pragma unroll
                for (int fm = 0; fm < 2; ++fm) {
                    acc[fm][fn] = __builtin_amdgcn_mfma_f32_16x16x32_bf16(bh, ah[fm][ks], acc[fm][fn], 0, 0, 0);
                    acc[fm][fn] = __builtin_amdgcn_mfma_f32_16x16x32_bf16(bl, ah[fm][ks], acc[fm][fn], 0, 0, 0);
                    acc[fm][fn] = __builtin_amdgcn_mfma_f32_16x16x32_bf16(bh, al[fm][ks], acc[fm][fn], 0, 0, 0);
                }
            }
        }
    };
    auto epilogueTile = [&](f32x4 (&acc)[2][4]) {
        float a1[2];
        #pragma unroll
        for (int fm = 0; fm < 2; ++fm) a1[fm] = c1 * sq1[wr + fm * 16 + (lane & 15)];
        #pragma unroll
        for (int fn = 0; fn < 4; ++fn) {
            f32x4 s  = *(const f32x4*)&sq2[wc + fn * 16 + (lane >> 4) * 4];
            f32x4 a2 = c1 * s;
            #pragma unroll
            for (int fm = 0; fm < 2; ++fm) {
                f32x4 o;
                #pragma unroll
                for (int r = 0; r < 4; ++r) {
                    float arg = fminf(fmaf(cm2, acc[fm][fn][r], a1[fm] + a2[r]), 0.0f);
                    o[r] = amp * __expf(arg);
                }
                int R = wr + fm * 16 + (lane & 15);
                int C = wc + fn * 16 + (lane >> 4) * 4;
                *(f32x4*)(Obuf + R * 512 + ((C * 4) ^ ((R & 7) << 4))) = o;
            }
        }
    };
    auto storeTile = [&](int mbase) {
        #pragma unroll
        for (int i = 0; i < 8; ++i) {
            int R = w * 16 + i * 2 + (lane >> 5);
            int c = lane & 31;
            f32x4 v = *(const f32x4*)(Obuf + R * 512 + ((c ^ (R & 7)) * 16));
            *(f32x4*)&out[(size_t)(n0 + R) * M + mbase + 4 * c] = v;
        }
    };

    // ---- stage A fragments (shared by both sub-tiles) + sq1 ----
    #pragma unroll
    for (int fm = 0; fm < 2; ++fm) {
        const int row = n0 + wr + fm * 16 + (lane & 15);
        const float4* Ap = (const float4*)(X1 + (size_t)row * DD) + (lane >> 4) * 2;
        float p = 0.0f;
        #pragma unroll
        for (int ks = 0; ks < 2; ++ks) {
            float4 f0 = Ap[ks * 8];
            float4 f1 = Ap[ks * 8 + 1];
            float xs[8] = { f0.x, f0.y, f0.z, f0.w, f1.x, f1.y, f1.z, f1.w };
            us8 hv, lv;
            #pragma unroll
            for (int e = 0; e < 8; ++e) {
                p = fmaf(xs[e], xs[e], p);
                unsigned short h = f2bf(xs[e]);
                hv[e] = h;
                lv[e] = f2bf(xs[e] - bf2f(h));
            }
            __builtin_memcpy(&ah[fm][ks], &hv, 16);
            __builtin_memcpy(&al[fm][ks], &lv, 16);
        }
        p += __shfl_xor(p, 16);
        p += __shfl_xor(p, 32);
        if ((w & 1) == 0 && (lane >> 4) == 0) sq1[wr + fm * 16 + lane] = p;
    }

    // ---- tile 0: stage B0, compute, epilogue ----
    {
        float4 f[8];
        loadB(m0, f);
        writeB(f);
    }
    barrier_lgkm();                  // b1: B0 + sq in LDS

    f32x4 accA[2][4] = {};
    computeTile(accA);
    epilogueTile(accA);
    barrier_lgkm();                  // b2: Obuf complete; B0 reads complete

    // ---- pipeline: issue B1 loads -> tile0 stores (stay in flight) -> B1 LDS ----
    {
        float4 f[8];
        loadB(m0 + TM, f);           // loads issued before stores (FIFO: waiting
        storeTile(m0);               //  for loads does NOT drain the stores)
        writeB(f);
    }
    barrier_lgkm();                  // b3: lgkm-only — tile0 stores NOT drained,
                                     //     they retire under tile1's compute
    f32x4 accB[2][4] = {};
    computeTile(accB);
    epilogueTile(accB);
    barrier_lgkm();                  // b4: Obuf complete

    storeTile(m0 + TM);              // kernel-end drain overlaps other blocks
}

extern "C" void kernel_launch(void* const* d_in, const int* in_sizes, int n_in,
                              void* d_out, int out_size, void* d_ws, size_t ws_size,
                              hipStream_t stream) {
    const float* X1 = (const float*)d_in[0];
    const float* X2 = (const float*)d_in[1];
    const float* lp = (const float*)d_in[2];
    const float* sf = (const float*)d_in[3];
    float* out = (float*)d_out;
    const int N = in_sizes[0] / DD;
    const int M = in_sizes[1] / DD;
    dim3 grid(M / (2 * TM), N / TN);   // 32 x 128 = 4096 blocks
    sqexp_kernel<<<grid, 256, 0, stream>>>(X1, X2, lp, sf, out, N, M);
}

// Round 13
// 80.691 us; speedup vs baseline: 5.9956x; 1.0154x over previous
//
#include <hip/hip_runtime.h>
#include <hip/hip_bf16.h>

#define DD 64      // feature dim K
#define TN 128     // output rows per block  (X1 rows)
#define TM 256     // output cols per block  (X2 rows)

typedef short short8 __attribute__((ext_vector_type(8)));
typedef unsigned short us8 __attribute__((ext_vector_type(8)));
typedef float f32x4 __attribute__((ext_vector_type(4)));

__device__ __forceinline__ float bf2f(unsigned short h) {
    union { unsigned u; float f; } v; v.u = ((unsigned)h) << 16;
    return v.f;
}
__device__ __forceinline__ unsigned short f2bf(float x) {
    __hip_bfloat16 b = __float2bfloat16(x);
    unsigned short u;
    __builtin_memcpy(&u, &b, 2);
    return u;
}

// lgkm-only workgroup barrier: orders LDS ops across the block WITHOUT the
// vmcnt(0) drain __syncthreads() emits. LDS WAR/RAW only needs lgkmcnt;
// global stores stay in flight across barriers and drain under later compute.
__device__ __forceinline__ void barrier_lgkm() {
    __builtin_amdgcn_sched_barrier(0);
    asm volatile("s_waitcnt lgkmcnt(0)" ::: "memory");
    __builtin_amdgcn_s_barrier();
    __builtin_amdgcn_sched_barrier(0);
}

__global__ __launch_bounds__(256, 2) void sqexp_kernel(
    const float* __restrict__ X1, const float* __restrict__ X2,
    const float* __restrict__ lp, const float* __restrict__ sfp,
    float* __restrict__ out, int N, int M)
{
    // B hi/lo bf16 tiles (2 x 32KB) during MFMA; SAME 64KB aliased as the f32
    // out-staging tile (64 rows x 1KB) during the two store phases.
    __shared__ __align__(16) unsigned char ldsbuf[TM * DD * 2 * 2];
    __shared__ float sq1[TN];
    __shared__ float sq2[TM];

    unsigned short* Bh = (unsigned short*)ldsbuf;
    unsigned short* Bl = (unsigned short*)(ldsbuf + TM * DD * 2);

    const int t    = threadIdx.x;
    const int w    = t >> 6;
    const int lane = t & 63;
    const int n0   = blockIdx.y * TN;
    const int m0   = blockIdx.x * TM;

    const int wr = (w >> 1) * 64;    // 2x2 wave grid: each wave 64 rows x 128 cols
    const int wc = (w & 1) * 128;

    // ---- B staging: one X2 row per thread -> hi/lo bf16 LDS (swizzled) + sq2 ----
    {
        const float4* Bp = (const float4*)(X2 + (size_t)(m0 + t) * DD);
        float4 bv[16];
        #pragma unroll
        for (int j = 0; j < 16; ++j) bv[j] = Bp[j];

        float s2 = 0.0f;
        #pragma unroll
        for (int c = 0; c < 8; ++c) {
            float4 f0 = bv[2 * c], f1 = bv[2 * c + 1];
            float xs[8] = { f0.x, f0.y, f0.z, f0.w, f1.x, f1.y, f1.z, f1.w };
            us8 hv, lv;
            #pragma unroll
            for (int e = 0; e < 8; ++e) {
                s2 = fmaf(xs[e], xs[e], s2);
                unsigned short h = f2bf(xs[e]);
                hv[e] = h;
                lv[e] = f2bf(xs[e] - bf2f(h));
            }
            int byte = t * 128 + ((c * 16) ^ ((t & 7) << 4));
            *(us8*)&Bh[byte >> 1] = hv;
            *(us8*)&Bl[byte >> 1] = lv;
        }
        sq2[t] = s2;
    }

    // ---- A fragments straight into registers + sq1 ----
    short8 ah[4][2], al[4][2];       // [fm][ks]
    #pragma unroll
    for (int fm = 0; fm < 4; ++fm) {
        const int row = n0 + wr + fm * 16 + (lane & 15);
        const float4* Ap = (const float4*)(X1 + (size_t)row * DD) + (lane >> 4) * 2;
        float p = 0.0f;
        #pragma unroll
        for (int ks = 0; ks < 2; ++ks) {
            float4 f0 = Ap[ks * 8];
            float4 f1 = Ap[ks * 8 + 1];
            float xs[8] = { f0.x, f0.y, f0.z, f0.w, f1.x, f1.y, f1.z, f1.w };
            us8 hv, lv;
            #pragma unroll
            for (int e = 0; e < 8; ++e) {
                p = fmaf(xs[e], xs[e], p);
                unsigned short h = f2bf(xs[e]);
                hv[e] = h;
                lv[e] = f2bf(xs[e] - bf2f(h));
            }
            __builtin_memcpy(&ah[fm][ks], &hv, 16);
            __builtin_memcpy(&al[fm][ks], &lv, 16);
        }
        p += __shfl_xor(p, 16);
        p += __shfl_xor(p, 32);
        if ((w & 1) == 0 && (lane >> 4) == 0) sq1[wr + fm * 16 + lane] = p;
    }
    barrier_lgkm();                  // b1: B tile + sq in LDS

    // ---- MFMA: cross = hiA*hiB + hiA*loB + loA*hiB ----
    f32x4 acc[4][8] = {};
    #pragma unroll
    for (int ks = 0; ks < 2; ++ks) {
        #pragma unroll
        for (int fn = 0; fn < 8; ++fn) {
            int brow = wc + fn * 16 + (lane & 15);
            int byte = brow * 128 + (((ks * 64) + (lane >> 4) * 16) ^ ((brow & 7) << 4));
            short8 bh = *(const short8*)&Bh[byte >> 1];
            short8 bl = *(const short8*)&Bl[byte >> 1];
            #pragma unroll
            for (int fm = 0; fm < 4; ++fm) {
                acc[fm][fn] = __builtin_amdgcn_mfma_f32_16x16x32_bf16(bh, ah[fm][ks], acc[fm][fn], 0, 0, 0);
                acc[fm][fn] = __builtin_amdgcn_mfma_f32_16x16x32_bf16(bl, ah[fm][ks], acc[fm][fn], 0, 0, 0);
                acc[fm][fn] = __builtin_amdgcn_mfma_f32_16x16x32_bf16(bh, al[fm][ks], acc[fm][fn], 0, 0, 0);
            }
        }
    }
    barrier_lgkm();                  // b2: all B-LDS reads done -> alias as Obuf

    const float lv_ = lp[0], sf = sfp[0];
    const float c1  = -0.5f / (lv_ * lv_);
    const float cm2 = -2.0f * c1;
    const float amp = sf * sf;

    float a1[4];
    #pragma unroll
    for (int fm = 0; fm < 4; ++fm) a1[fm] = c1 * sq1[wr + fm * 16 + (lane & 15)];

    // ---- two store phases: phase p covers block rows [64p, 64p+64).
    //      Stores are never vmcnt-waited: they stay in flight across phases
    //      and across the block boundary, draining under later compute. ----
    #pragma unroll
    for (int p = 0; p < 2; ++p) {
        if ((w >> 1) == p) {
            #pragma unroll
            for (int fn = 0; fn < 8; ++fn) {
                f32x4 s  = *(const f32x4*)&sq2[wc + fn * 16 + (lane >> 4) * 4];
                f32x4 a2 = c1 * s;
                #pragma unroll
                for (int fm = 0; fm < 4; ++fm) {
                    f32x4 o;
                    #pragma unroll
                    for (int r = 0; r < 4; ++r) {
                        float arg = fminf(fmaf(cm2, acc[fm][fn][r], a1[fm] + a2[r]), 0.0f);
                        o[r] = amp * __expf(arg);
                    }
                    int R = fm * 16 + (lane & 15);               // phase-local row
                    int C = wc + fn * 16 + (lane >> 4) * 4;
                    *(f32x4*)(ldsbuf + R * 1024 + ((C * 4) ^ ((R & 7) << 4))) = o;
                }
            }
        }
        barrier_lgkm();              // Obuf(phase p) complete

        #pragma unroll
        for (int i = 0; i < 16; ++i) {
            int R = w * 16 + i;
            f32x4 v = *(const f32x4*)(ldsbuf + R * 1024 + ((lane ^ (R & 7)) * 16));
            size_t off = (size_t)(n0 + p * 64 + R) * M + m0 + 4 * lane;
            *(f32x4*)&out[off] = v;
        }
        barrier_lgkm();              // Obuf ds_reads done (LDS WAR cleared; the
                                     // global stores keep draining, un-waited)
    }
}

extern "C" void kernel_launch(void* const* d_in, const int* in_sizes, int n_in,
                              void* d_out, int out_size, void* d_ws, size_t ws_size,
                              hipStream_t stream) {
    const float* X1 = (const float*)d_in[0];
    const float* X2 = (const float*)d_in[1];
    const float* lp = (const float*)d_in[2];
    const float* sf = (const float*)d_in[3];
    float* out = (float*)d_out;
    const int N = in_sizes[0] / DD;
    const int M = in_sizes[1] / DD;
    dim3 grid(M / TM, N / TN);   // 32 x 64 = 2048 blocks
    sqexp_kernel<<<grid, 256, 0, stream>>>(X1, X2, lp, sf, out, N, M);
}